// Round 9
// baseline (191.229 us; speedup 1.0000x reference)
//
#include <hip/hip_runtime.h>
#include <math.h>

// ---------------------------------------------------------------------------
// TwoDimEquivalent: B=8192 independent nonlinear scans of length T=2048.
// R14: ROW-SPLIT OCCUPANCY -- 2x waves/CU at identical work and bytes.
//   Model re-fit (R5-R13): kernel is LATENCY-bound, TLP-starved. Evidence:
//   R7 at 4 waves/SIMD ran 115 cyc/step-SIMD vs 266 at 2 waves/SIMD (2.3x);
//   R13 (poly, no LDS) regressed to VALU-issue at 2 waves/SIMD; R8 (LLC-
//   resident) unchanged -> not BW; bytes/2.9TB/s fit was coincidence of
//   constant 8 waves/CU. Fix: 32 rows/wave, lanes l and l+32 DUPLICATE the
//   same row (wave-wide VALU makes it free; same-addr LDS reads broadcast).
//   4096 waves = 16/CU = 4/SIMD, same total row-steps, same bytes.
//  * LUT: SCALAR g table (2049 floats, 8.2 KB) read as tab[i0],tab[i0+1]
//    (ds_read2_b32; addresses spread over all 32 banks -- better than the
//    16-bank float2 pair table). Same h=1/32 accuracy.
//  * LDS: 8.2 KB tab + 4 x 32x33 staging (16.9 KB) = 25.1 KB/block ->
//    4 blocks/CU. VGPR target <=128 (zz64+G16+~20).
//  * Wave-autonomous (R11): no barriers in main loop (one after tab fill);
//    vmcnt never force-drained; per-step u read direct from sb (R12 null).
//  * 16 chunks x 128 steps, 128-step warmup; window = 32 steps; z flushed
//    per 64 cols through sb scratch (2x32-col transpose, 2-way banks free).
// History: R5 151.9 (warm 57). R7 2x waves+1.5x work: per-SIMD rate 2.3x
// better -> TLP-starved. R8 LLC-touch: null -> not BW-bound; graded runs
// ~2.6x-degraded env (DVFS) -> optimize warm. R9 counted barriers: cold
// dispatch 147->58. R10 1 wave/SIMD: regress. R11/R12 LDS restructure:
// null. R13 poly: VALU floor regress. R14 predict: warm 30-40 (else 2.9
// TB/s wall is real), graded 85-110.
// ---------------------------------------------------------------------------

#define Bsz   8192
#define Tlen  2048
#define TP1   2049
#define NQ    64
#define NG    2049                // scalar g samples, s = j/32 on [0,64]
#define INV_H 32.0f
#define CHUNKS 16
#define CLEN  128
#define WARM  128
#define BLOCK 256
#define RPW   32                  // rows per wave (l and l+32 duplicate)
#define SROW  33                  // staging row stride (floats)
#define SIM_GRID (64 * CHUNKS)    // 1024: 64 row-blocks(128 rows) x 16 chunks

#define WS_TAB 128                // scalar g table offset (floats) in d_ws

// LDS-visibility barrier (after tab fill only); vmcnt NOT drained.
__device__ __forceinline__ void bar_nodrain() {
    asm volatile("s_waitcnt lgkmcnt(0)" ::: "memory");
    __builtin_amdgcn_s_barrier();
}
// Intra-wave DS fence: all my ds ops complete; compiler may not reorder.
__device__ __forceinline__ void ds_fence() {
    asm volatile("s_waitcnt lgkmcnt(0)" ::: "memory");
}

// --------------------------- setup: build LUT ------------------------------
__global__ __launch_bounds__(256) void setup_kernel(float* __restrict__ ws,
                                                    float* __restrict__ out) {
    __shared__ float  fx[NQ], fw[NQ];
    __shared__ double inv[NQ + 1];
    const int tid = threadIdx.x;
    if (tid <= NQ) inv[tid] = (tid == 0) ? 0.0 : 1.0 / (double)tid;
    __syncthreads();
    if (tid < NQ) {
        // Newton on P_64: guess err ~3e-4 -> 3 updates reach ~1e-15,
        // 4th pass evaluates pp at converged z (no update).
        double z = cos(3.14159265358979323846 * (tid + 0.75) / (NQ + 0.5));
        double p1 = 1.0, p2 = 0.0, pp = 1.0;
        for (int it = 0; it < 4; ++it) {
            p1 = 1.0; p2 = 0.0;
            for (int j = 1; j <= NQ; ++j) {
                double p3 = p2; p2 = p1;
                p1 = ((2.0 * j - 1.0) * z * p2 - (j - 1.0) * p3) * inv[j];
            }
            pp = NQ * (z * p1 - p2) / (z * z - 1.0);
            if (it < 3) z -= p1 / pp;
        }
        double w  = 2.0 / ((1.0 - z * z) * pp * pp);
        double xs = z * 5.0;                       // node scaled to [-5,5]
        fx[tid] = (float)xs;                       // f32 cast, like reference
        fw[tid] = (float)(w * 5.0 * exp(-0.5 * xs * xs) * 0.3989422804014327);
    }
    __syncthreads();
    const int j = blockIdx.x * 256 + tid;          // grid 32x256 = 8192
    if (j < NG) {                                  // g(s_j), s_j = j/32
        const float d = sqrtf((float)j * (1.0f / INV_H));
        float acc = 0.0f;
        #pragma unroll 8
        for (int q = 0; q < NQ; ++q) {
            float t = tanhf(d * fx[q]);
            acc = fmaf(fw[q], 1.0f - t * t, acc);
        }
        ws[WS_TAB + j] = acc;
    }
    out[(size_t)j * TP1] = 0.0f;                   // z_hist[:,0] = 0
}

// ------------------------------ main scan ----------------------------------
__device__ __forceinline__ float step_one(float uu, float& k1, float& k2,
                                          float& v, const float* tab) {
    float s   = fmaf(k1, k1, fmaf(k2, k2, uu * uu));      // delta^2
    float idx = fminf(s * INV_H, 2046.999f);
    int   i0  = (int)idx;
    float f   = idx - (float)i0;
    float ga  = tab[i0];                                  // ds_read2_b32
    float gb  = tab[i0 + 1];                              //  (paired)
    float g   = fmaf(f, gb - ga, ga);                     // gauss_int
    float gv  = g * v;
    float nk1 = fmaf(k1, fmaf(0.2f, g, 0.8f), 0.10f * gv);
    float nk2 = fmaf(k2, fmaf(0.1f, g, 0.8f), 0.38f * gv);
    v  = fmaf(0.2f, uu - v, v);
    k1 = nk1; k2 = nk2;
    return fmaf(2.8f, nk1, -2.2f * nk2);
}

// Load next window: 4 float4, rows 8r+srow, 128 B contiguous per 8-lane group
#define GLOAD(G, t) { _Pragma("unroll")                                       \
    for (int r = 0; r < 4; ++r)                                               \
        G[r] = *(const float4*)(up + (size_t)r * 8 * Tlen + (t)); }

// Stage window into per-wave LDS buffer (16 ds_write_b32 per lane)
#define STAGE(G) { asm volatile("" ::: "memory");  _Pragma("unroll")          \
    for (int r = 0; r < 4; ++r) {                                             \
        int b8 = (8 * r + srow) * SROW + scol;                                \
        sb[b8] = G[r].x; sb[b8+1] = G[r].y; sb[b8+2] = G[r].z;                \
        sb[b8+3] = G[r].w; }                                                  \
    ds_fence(); }

// Flush 64 z-cols for the wave's 32 rows through sb scratch (sb must be
// free). Lanes<32 write (dup halves identical); stores: 2 rows x 128 B.
#define FLUSH(h) { const int cb = t_out + 1 + 64 * (h);                       \
    _Pragma("unroll") for (int p = 0; p < 2; ++p) {                           \
        asm volatile("" ::: "memory");                                        \
        if (l < 32) { _Pragma("unroll") for (int j = 0; j < 32; ++j)          \
            sb[lbase + j] = zz[p * 32 + j]; }                                 \
        ds_fence();                                                           \
        _Pragma("unroll") for (int kk = 0; kk < 16; ++kk) {                   \
            int row = 2 * kk + (l >> 5);                                      \
            out[(size_t)(rowb + row) * TP1 + cb + p * 32 + (l & 31)] =        \
                sb[row * SROW + (l & 31)];                                    \
        }                                                                     \
        ds_fence(); } }

__global__ __launch_bounds__(BLOCK, 4) void sim_kernel(const float* __restrict__ u,
                                                       const float* __restrict__ ws,
                                                       float* __restrict__ out) {
    __shared__ float s_tabS[NG];                   // 8.2 KB scalar g table
    __shared__ float s_st[4][RPW * SROW];          // 4 x 4.2 KB per-wave bufs
    const int tid = threadIdx.x;
    const int w   = tid >> 6;                      // wave id (4)
    const int l   = tid & 63;                      // lane
    float* sb = s_st[w];

    const int c    = blockIdx.x >> 6;              // chunk id (16)
    const int rb   = blockIdx.x & 63;              // row-block id (64)
    const int rowb = rb * 128 + w * RPW;           // wave's first row
    const int t_out   = c * CLEN;                  // first owned step
    const int t_begin = (t_out >= WARM) ? (t_out - WARM) : 0;   // c=0 -> 0

    // staging lane map: lane l covers row (8r + srow), 16 B at offset scol
    const int srow = l >> 3;                       // 0..7
    const int scol = (l & 7) * 4;                  // 0,4,...,28
    const float* __restrict__ up = u + (size_t)(rowb + srow) * Tlen + scol;
    const int lbase = (l & 31) * SROW;             // my row's staging base

    // Issue the first window FIRST so cold misses start immediately.
    float4 G[4];
    GLOAD(G, t_begin);

    {   // scalar tab fill: 256 threads x 8 floats + 1 tail
        const float* g = ws + WS_TAB;
        float4 a0 = *(const float4*)(g + tid * 8);
        float4 a1 = *(const float4*)(g + tid * 8 + 4);
        *(float4*)&s_tabS[tid * 8]     = a0;       // 32 B/thread, aligned
        *(float4*)&s_tabS[tid * 8 + 4] = a1;
        if (tid == 0) s_tabS[2048] = g[2048];
    }
    bar_nodrain();                                 // the ONLY block barrier

    // Prime: sb = window(t_begin), G = window(t_begin+32)
    STAGE(G);
    GLOAD(G, t_begin + 32);

    float k1 = 0.f, k2 = 0.f, v = 0.f;

    // ---------------- warmup: 0 or 4 windows, z discarded ----------------
    for (int tb = t_begin; tb < t_out; tb += 32) {
        #pragma unroll
        for (int t2 = 0; t2 < 32; ++t2)
            step_one(sb[lbase + t2], k1, k2, v, s_tabS);
        ds_fence();                                // window reads retired
        STAGE(G);                                  // sb <- window(tb+32)
        GLOAD(G, tb + 64);                         // <= t_out+32 <= 1952 ok
    }

    // ---------------- output: 4 windows of 32 steps ----------------
    float zz[64];
    #pragma unroll
    for (int k2w = 0; k2w < 4; ++k2w) {
        #pragma unroll
        for (int t2 = 0; t2 < 32; ++t2)
            zz[(k2w & 1) * 32 + t2] = step_one(sb[lbase + t2], k1, k2, v, s_tabS);
        ds_fence();                                // window reads retired
        if (k2w == 1) FLUSH(0);                    // cols [t_out+1, +65)
        if (k2w == 3) break;
        STAGE(G);                                  // sb <- window(tb+32)
        int tn = t_out + 32 * k2w + 64;            // clamp: tail of c=15
        if (tn > Tlen - 32) tn = Tlen - 32;
        GLOAD(G, tn);
    }
    FLUSH(1);                                      // cols [t_out+65, +129)
}

// ------------------------------ launcher -----------------------------------
extern "C" void kernel_launch(void* const* d_in, const int* in_sizes, int n_in,
                              void* d_out, int out_size, void* d_ws, size_t ws_size,
                              hipStream_t stream) {
    const float* u = (const float*)d_in[0];
    float* out = (float*)d_out;
    float* ws  = (float*)d_ws;                     // needs ~9 KB
    setup_kernel<<<32, 256, 0, stream>>>(ws, out);
    sim_kernel<<<SIM_GRID, BLOCK, 0, stream>>>(u, ws, out);
}

// Round 10
// 147.674 us; speedup vs baseline: 1.2949x; 1.2949x over previous
//
#include <hip/hip_runtime.h>
#include <math.h>

// ---------------------------------------------------------------------------
// TwoDimEquivalent: B=8192 independent nonlinear scans of length T=2048.
// R15: ROW-SPLIT OCCUPANCY, SPILL-FREE (the experiment R14 was meant to be).
//   R14 post-mortem: launch_bounds(256,4) capped VGPR at 64, kernel needed
//   ~90 (zz[64]) -> ~26 regs spilled: WRITE 163 MB (+90 scratch), FETCH
//   97 MB (+22), warm 97 us = 266 MB / 2.74 TB/s. Occupancy never tested.
//   Two degenerate models fit ALL rounds (bytes ~ steps everywhere):
//   (A) ~2.8-2.9 TB/s transfer wall: time = hbm_bytes / 2.8.
//   (B) latency-bound ~250 cyc/step/SIMD, TLP-starved at 8 waves/CU.
//   R15 discriminates: same work+bytes, 2x waves (4096 = 16/CU = 4/SIMD).
//   32 real rows/wave, lanes l,l+32 duplicate row l&31 (free on wave64;
//   same-addr LDS reads broadcast). VGPR fits 64 by flushing z every 32
//   steps (zz[32]): G[4]=16 + zz 32 + state 3 + misc ~ 62.
//  * Wave-autonomous barrier-free schedule (R11/R12): private [32][33]
//    staging buf/wave, scalar g table (8.2 KB), ds_read2_b32 gather,
//    one block barrier after table fill, vmcnt never drained.
//  * LDS: 8.2 + 4 x 4.2 = 25.1 KB -> not the occupancy limiter (40 KB cap).
//  * 16 chunks x 128 steps, WARM 128 (bytes/accuracy unchanged).
// History: R5 151.9. R7 +bytes regress. R8 LLC-touch null -> graded runs
// ~2.6x-degraded env; optimize warm. R9 counted barriers fixed cold
// dispatch. R10 1 wave/SIMD regress. R11/R12 LDS nulls. R13 poly: VALU
// floor. R14 spill-confounded. R15 predict: no-spill (WRITE ~75 MB) then
// Model B -> warm 30-40 / graded 85-110; Model A -> warm ~55 / graded ~145
// (then: transfer wall, attack bytes).
// ---------------------------------------------------------------------------

#define Bsz   8192
#define Tlen  2048
#define TP1   2049
#define NQ    64
#define NG    2049                // scalar g samples, s = j/32 on [0,64]
#define INV_H 32.0f
#define CHUNKS 16
#define CLEN  128
#define WARM  128
#define BLOCK 256
#define RPW   32                  // real rows per wave (lanes dup pairwise)
#define SROW  33                  // staging row stride (floats)
#define SIM_GRID (64 * CHUNKS)    // 1024: 64 row-blocks(128 rows) x 16 chunks

#define WS_TAB 128                // scalar g table offset (floats) in d_ws

// LDS-visibility barrier (after tab fill only); vmcnt NOT drained.
__device__ __forceinline__ void bar_nodrain() {
    asm volatile("s_waitcnt lgkmcnt(0)" ::: "memory");
    __builtin_amdgcn_s_barrier();
}
// Intra-wave DS fence: all my ds ops complete; compiler may not reorder.
__device__ __forceinline__ void ds_fence() {
    asm volatile("s_waitcnt lgkmcnt(0)" ::: "memory");
}

// --------------------------- setup: build LUT ------------------------------
__global__ __launch_bounds__(256) void setup_kernel(float* __restrict__ ws,
                                                    float* __restrict__ out) {
    __shared__ float  fx[NQ], fw[NQ];
    __shared__ double inv[NQ + 1];
    const int tid = threadIdx.x;
    if (tid <= NQ) inv[tid] = (tid == 0) ? 0.0 : 1.0 / (double)tid;
    __syncthreads();
    if (tid < NQ) {
        // Newton on P_64: guess err ~3e-4 -> 3 updates reach ~1e-15,
        // 4th pass evaluates pp at converged z (no update).
        double z = cos(3.14159265358979323846 * (tid + 0.75) / (NQ + 0.5));
        double p1 = 1.0, p2 = 0.0, pp = 1.0;
        for (int it = 0; it < 4; ++it) {
            p1 = 1.0; p2 = 0.0;
            for (int j = 1; j <= NQ; ++j) {
                double p3 = p2; p2 = p1;
                p1 = ((2.0 * j - 1.0) * z * p2 - (j - 1.0) * p3) * inv[j];
            }
            pp = NQ * (z * p1 - p2) / (z * z - 1.0);
            if (it < 3) z -= p1 / pp;
        }
        double w  = 2.0 / ((1.0 - z * z) * pp * pp);
        double xs = z * 5.0;                       // node scaled to [-5,5]
        fx[tid] = (float)xs;                       // f32 cast, like reference
        fw[tid] = (float)(w * 5.0 * exp(-0.5 * xs * xs) * 0.3989422804014327);
    }
    __syncthreads();
    const int j = blockIdx.x * 256 + tid;          // grid 32x256 = 8192
    if (j < NG) {                                  // g(s_j), s_j = j/32
        const float d = sqrtf((float)j * (1.0f / INV_H));
        float acc = 0.0f;
        #pragma unroll 8
        for (int q = 0; q < NQ; ++q) {
            float t = tanhf(d * fx[q]);
            acc = fmaf(fw[q], 1.0f - t * t, acc);
        }
        ws[WS_TAB + j] = acc;
    }
    out[(size_t)j * TP1] = 0.0f;                   // z_hist[:,0] = 0
}

// ------------------------------ main scan ----------------------------------
__device__ __forceinline__ float step_one(float uu, float& k1, float& k2,
                                          float& v, const float* tab) {
    float s   = fmaf(k1, k1, fmaf(k2, k2, uu * uu));      // delta^2
    float idx = fminf(s * INV_H, 2046.999f);
    int   i0  = (int)idx;
    float f   = idx - (float)i0;
    float ga  = tab[i0];                                  // ds_read2_b32
    float gb  = tab[i0 + 1];                              //  (paired)
    float g   = fmaf(f, gb - ga, ga);                     // gauss_int
    float gv  = g * v;
    float nk1 = fmaf(k1, fmaf(0.2f, g, 0.8f), 0.10f * gv);
    float nk2 = fmaf(k2, fmaf(0.1f, g, 0.8f), 0.38f * gv);
    v  = fmaf(0.2f, uu - v, v);
    k1 = nk1; k2 = nk2;
    return fmaf(2.8f, nk1, -2.2f * nk2);
}

// Load next window: 4 float4; (r,srow,scol) over 64 lanes covers 32 rows
// x 128 B, each lane a DISTINCT 16 B (no duplication in global traffic).
#define GLOAD(G, t) { _Pragma("unroll")                                       \
    for (int r = 0; r < 4; ++r)                                               \
        G[r] = *(const float4*)(up + (size_t)r * 8 * Tlen + (t)); }

// Stage window into per-wave LDS buffer (16 ds_write_b32 per lane)
#define STAGE(G) { asm volatile("" ::: "memory");  _Pragma("unroll")          \
    for (int r = 0; r < 4; ++r) {                                             \
        int b8 = (8 * r + srow) * SROW + scol;                                \
        sb[b8] = G[r].x; sb[b8+1] = G[r].y; sb[b8+2] = G[r].z;                \
        sb[b8+3] = G[r].w; }                                                  \
    ds_fence(); }

// Flush one 32-col window for the wave's 32 rows through sb scratch.
// Write: lanes<32, banks (l+j)%32 conflict-free. Read: 2 lanes/bank (free).
// Stores: 2 rows x 128 B contiguous per iteration.
#define FLUSH(kw) { const int cb = t_out + 1 + 32 * (kw);                     \
    asm volatile("" ::: "memory");                                            \
    if (l < 32) { _Pragma("unroll") for (int j = 0; j < 32; ++j)              \
        sb[lbase + j] = zz[j]; }                                              \
    ds_fence();                                                               \
    _Pragma("unroll") for (int kk = 0; kk < 16; ++kk) {                       \
        int row = 2 * kk + (l >> 5);                                          \
        out[(size_t)(rowb + row) * TP1 + cb + (l & 31)] =                     \
            sb[row * SROW + (l & 31)];                                        \
    }                                                                         \
    ds_fence(); }

__global__ __launch_bounds__(BLOCK, 4) void sim_kernel(const float* __restrict__ u,
                                                       const float* __restrict__ ws,
                                                       float* __restrict__ out) {
    __shared__ float s_tabS[NG];                   // 8.2 KB scalar g table
    __shared__ float s_st[4][RPW * SROW];          // 4 x 4.2 KB per-wave bufs
    const int tid = threadIdx.x;
    const int w   = tid >> 6;                      // wave id (4)
    const int l   = tid & 63;                      // lane
    float* sb = s_st[w];

    const int c    = blockIdx.x >> 6;              // chunk id (16)
    const int rb   = blockIdx.x & 63;              // row-block id (64)
    const int rowb = rb * 128 + w * RPW;           // wave's first row
    const int t_out   = c * CLEN;                  // first owned step
    const int t_begin = (t_out >= WARM) ? (t_out - WARM) : 0;   // c=0 -> 0

    // staging lane map: lane l covers row (8r + srow), 16 B at offset scol
    const int srow = l >> 3;                       // 0..7
    const int scol = (l & 7) * 4;                  // 0,4,...,28
    const float* __restrict__ up = u + (size_t)(rowb + srow) * Tlen + scol;
    const int lbase = (l & 31) * SROW;             // my row's staging base

    // Issue the first window FIRST so cold misses start immediately.
    float4 G[4];
    GLOAD(G, t_begin);

    {   // scalar tab fill: 256 threads x 8 floats + 1 tail
        const float* g = ws + WS_TAB;
        float4 a0 = *(const float4*)(g + tid * 8);
        float4 a1 = *(const float4*)(g + tid * 8 + 4);
        *(float4*)&s_tabS[tid * 8]     = a0;       // 32 B/thread, aligned
        *(float4*)&s_tabS[tid * 8 + 4] = a1;
        if (tid == 0) s_tabS[2048] = g[2048];
    }
    bar_nodrain();                                 // the ONLY block barrier

    // Prime: sb = window(t_begin), G = window(t_begin+32)
    STAGE(G);
    GLOAD(G, t_begin + 32);

    float k1 = 0.f, k2 = 0.f, v = 0.f;

    // ---------------- warmup: 0 or 4 windows, z discarded ----------------
    for (int tb = t_begin; tb < t_out; tb += 32) {
        #pragma unroll
        for (int t2 = 0; t2 < 32; ++t2)
            step_one(sb[lbase + t2], k1, k2, v, s_tabS);
        ds_fence();                                // window reads retired
        STAGE(G);                                  // sb <- window(tb+32)
        GLOAD(G, tb + 64);                         // <= t_out+32 <= 1952 ok
    }

    // ---------------- output: 4 windows of 32 steps ----------------
    float zz[32];
    #pragma unroll
    for (int kw = 0; kw < 4; ++kw) {
        #pragma unroll
        for (int t2 = 0; t2 < 32; ++t2)
            zz[t2] = step_one(sb[lbase + t2], k1, k2, v, s_tabS);
        ds_fence();                                // window reads retired
        FLUSH(kw);                                 // cols [t_out+1+32kw, +32)
        if (kw == 3) break;
        STAGE(G);                                  // sb <- next window
        int tn = t_out + 32 * kw + 64;             // clamp: tail of c=15
        if (tn > Tlen - 32) tn = Tlen - 32;
        GLOAD(G, tn);
    }
}

// ------------------------------ launcher -----------------------------------
extern "C" void kernel_launch(void* const* d_in, const int* in_sizes, int n_in,
                              void* d_out, int out_size, void* d_ws, size_t ws_size,
                              hipStream_t stream) {
    const float* u = (const float*)d_in[0];
    float* out = (float*)d_out;
    float* ws  = (float*)d_ws;                     // needs ~9 KB
    setup_kernel<<<32, 256, 0, stream>>>(ws, out);
    sim_kernel<<<SIM_GRID, BLOCK, 0, stream>>>(u, ws, out);
}

// Round 11
// 144.842 us; speedup vs baseline: 1.3203x; 1.0195x over previous
//
#include <hip/hip_runtime.h>
#include <math.h>

// ---------------------------------------------------------------------------
// TwoDimEquivalent: B=8192 independent nonlinear scans of length T=2048.
// R16: STEP-COUNT REDUCTION for the graded regime (WARM 128->96).
//   Model after R15's discriminator: warm (boost clock) sits on an
//   effective ~2.7-2.9 TB/s wall for this scatter R/W mix (compulsory
//   ~145 MB -> ~52 us floor; we're at 55-57: done). Graded runs at reduced
//   core clock with full HBM speed (graded/warm ratio 1.97-2.28 for
//   byte-heavy variants vs 2.5-2.7 for compute-lean) -> graded is
//   STEP-bound. Lever: fewer total steps. WARM=96 keeps relative warm-in
//   error ~0.92^96 ~ 3e-4 (z error ~1e-4, well under tolerance; absmax
//   0.0078125 identical across LUT AND poly rounds = harness floor).
//   Steps 3968 -> 3488 per row (x0.879).
//  * Chassis = R12 (graded-best 145.3): 64 rows/wave non-dup (R15's dup
//    doubles issue per row-step -- wrong direction for a step-bound
//    regime), wave-autonomous, no main-loop barriers, vmcnt never drained.
//  * Dropped: READBACK/U regs (R12-vs-R15 null) -> direct sb step reads;
//    zz[32] + flush every 32-step window -> VGPR ~90, no spill at cap 128.
//  * LUT: scalar g table (8.2 KB, R15-proven ds_read2_b32 pair).
//  * LDS: 8.2 + 4 x 8.25 (per-wave [64][33] staging) = 41.2 KB.
// History: R5 151.9. R7 +bytes regress. R8 LLC-touch null. R9 counted
// barriers fixed cold dispatch (147->58). R10 1 wave/SIMD regress.
// R11/R12 LDS nulls. R13 poly = VALU floor. R14 spill-confounded.
// R15 2x TLP null -> byte wall warm / step-bound graded.
// R16 predict: absmax unchanged; warm 50-54; graded 125-140 if
// step-coupled, else ~145 -> declare environmental plateau.
// ---------------------------------------------------------------------------

#define Bsz   8192
#define Tlen  2048
#define TP1   2049
#define NQ    64
#define NG    2049                // scalar g samples, s = j/32 on [0,64]
#define INV_H 32.0f
#define CHUNKS 16
#define CLEN  128
#define WARM  96                  // 3 windows; decay margin ~3e-4
#define BLOCK 256
#define SROW  33                  // staging row stride (floats)
#define SIM_GRID (32 * CHUNKS)    // 512: 32 row-blocks(256 rows) x 16 chunks

#define WS_TAB 128                // scalar g table offset (floats) in d_ws

// LDS-visibility barrier (after tab fill only); vmcnt NOT drained.
__device__ __forceinline__ void bar_nodrain() {
    asm volatile("s_waitcnt lgkmcnt(0)" ::: "memory");
    __builtin_amdgcn_s_barrier();
}
// Intra-wave DS fence: all my ds ops complete; compiler may not reorder.
__device__ __forceinline__ void ds_fence() {
    asm volatile("s_waitcnt lgkmcnt(0)" ::: "memory");
}

// --------------------------- setup: build LUT ------------------------------
__global__ __launch_bounds__(256) void setup_kernel(float* __restrict__ ws,
                                                    float* __restrict__ out) {
    __shared__ float  fx[NQ], fw[NQ];
    __shared__ double inv[NQ + 1];
    const int tid = threadIdx.x;
    if (tid <= NQ) inv[tid] = (tid == 0) ? 0.0 : 1.0 / (double)tid;
    __syncthreads();
    if (tid < NQ) {
        // Newton on P_64: guess err ~3e-4 -> 3 updates reach ~1e-15,
        // 4th pass evaluates pp at converged z (no update).
        double z = cos(3.14159265358979323846 * (tid + 0.75) / (NQ + 0.5));
        double p1 = 1.0, p2 = 0.0, pp = 1.0;
        for (int it = 0; it < 4; ++it) {
            p1 = 1.0; p2 = 0.0;
            for (int j = 1; j <= NQ; ++j) {
                double p3 = p2; p2 = p1;
                p1 = ((2.0 * j - 1.0) * z * p2 - (j - 1.0) * p3) * inv[j];
            }
            pp = NQ * (z * p1 - p2) / (z * z - 1.0);
            if (it < 3) z -= p1 / pp;
        }
        double w  = 2.0 / ((1.0 - z * z) * pp * pp);
        double xs = z * 5.0;                       // node scaled to [-5,5]
        fx[tid] = (float)xs;                       // f32 cast, like reference
        fw[tid] = (float)(w * 5.0 * exp(-0.5 * xs * xs) * 0.3989422804014327);
    }
    __syncthreads();
    const int j = blockIdx.x * 256 + tid;          // grid 32x256 = 8192
    if (j < NG) {                                  // g(s_j), s_j = j/32
        const float d = sqrtf((float)j * (1.0f / INV_H));
        float acc = 0.0f;
        #pragma unroll 8
        for (int q = 0; q < NQ; ++q) {
            float t = tanhf(d * fx[q]);
            acc = fmaf(fw[q], 1.0f - t * t, acc);
        }
        ws[WS_TAB + j] = acc;
    }
    out[(size_t)j * TP1] = 0.0f;                   // z_hist[:,0] = 0
}

// ------------------------------ main scan ----------------------------------
__device__ __forceinline__ float step_one(float uu, float& k1, float& k2,
                                          float& v, const float* tab) {
    float s   = fmaf(k1, k1, fmaf(k2, k2, uu * uu));      // delta^2
    float idx = fminf(s * INV_H, 2046.999f);
    int   i0  = (int)idx;
    float f   = idx - (float)i0;
    float ga  = tab[i0];                                  // ds_read2_b32
    float gb  = tab[i0 + 1];                              //  (paired)
    float g   = fmaf(f, gb - ga, ga);                     // gauss_int
    float gv  = g * v;
    float nk1 = fmaf(k1, fmaf(0.2f, g, 0.8f), 0.10f * gv);
    float nk2 = fmaf(k2, fmaf(0.1f, g, 0.8f), 0.38f * gv);
    v  = fmaf(0.2f, uu - v, v);
    k1 = nk1; k2 = nk2;
    return fmaf(2.8f, nk1, -2.2f * nk2);
}

// Load next window: 8 float4/lane; 64 lanes cover 64 rows x 128 B, each
// lane a DISTINCT 16 B (rows 8r+srow, byte offset 16*scol/4).
#define GLOAD(G, t) { _Pragma("unroll")                                       \
    for (int r = 0; r < 8; ++r)                                               \
        G[r] = *(const float4*)(up + (size_t)r * 8 * Tlen + (t)); }

// Stage window into per-wave LDS buffer (32 ds_write_b32 per lane)
#define STAGE(G) { asm volatile("" ::: "memory");  _Pragma("unroll")          \
    for (int r = 0; r < 8; ++r) {                                             \
        int b8 = (8 * r + srow) * SROW + scol;                                \
        sb[b8] = G[r].x; sb[b8+1] = G[r].y; sb[b8+2] = G[r].z;                \
        sb[b8+3] = G[r].w; }                                                  \
    ds_fence(); }

// Flush one 32-col window for the wave's 64 rows through sb scratch.
// Write: lane l -> row l, banks (l+j)%32 free. Read: rows 2kk,2kk+1 x 32
// cols = 2 x 128 B per store instr; banks 2 lanes/bank (free).
#define FLUSH(kw) { const int cb = t_out + 1 + 32 * (kw);                     \
    asm volatile("" ::: "memory");                                            \
    _Pragma("unroll") for (int j = 0; j < 32; ++j)                            \
        sb[lbase + j] = zz[j];                                                \
    ds_fence();                                                               \
    _Pragma("unroll") for (int kk = 0; kk < 32; ++kk) {                       \
        int row = 2 * kk + (l >> 5);                                          \
        out[(size_t)(rowb + row) * TP1 + cb + (l & 31)] =                     \
            sb[row * SROW + (l & 31)];                                        \
    }                                                                         \
    ds_fence(); }

__global__ __launch_bounds__(BLOCK, 2) void sim_kernel(const float* __restrict__ u,
                                                       const float* __restrict__ ws,
                                                       float* __restrict__ out) {
    __shared__ float s_tabS[NG];                   // 8.2 KB scalar g table
    __shared__ float s_st[4][64 * SROW];           // 4 x 8.25 KB per-wave bufs
    const int tid = threadIdx.x;
    const int w   = tid >> 6;                      // wave id (4)
    const int l   = tid & 63;                      // lane
    float* sb = s_st[w];

    const int c    = blockIdx.x >> 5;              // chunk id (16)
    const int bb   = blockIdx.x & 31;              // row-block id (32)
    const int rowb = bb * 256 + w * 64;            // wave's first row
    const int t_out   = c * CLEN;                  // first owned step
    const int t_begin = (t_out >= WARM) ? (t_out - WARM) : 0;   // c=0 -> 0

    // staging lane map: lane l covers row (8r + srow), 16 B at offset scol
    const int srow = l >> 3;                       // 0..7
    const int scol = (l & 7) * 4;                  // 0,4,...,28
    const float* __restrict__ up = u + (size_t)(rowb + srow) * Tlen + scol;
    const int lbase = l * SROW;                    // my row's staging base

    // Issue the first window FIRST so cold misses start immediately.
    float4 G[8];
    GLOAD(G, t_begin);

    {   // scalar tab fill: 256 threads x 8 floats + 1 tail
        const float* g = ws + WS_TAB;
        float4 a0 = *(const float4*)(g + tid * 8);
        float4 a1 = *(const float4*)(g + tid * 8 + 4);
        *(float4*)&s_tabS[tid * 8]     = a0;       // 32 B/thread, aligned
        *(float4*)&s_tabS[tid * 8 + 4] = a1;
        if (tid == 0) s_tabS[2048] = g[2048];
    }
    bar_nodrain();                                 // the ONLY block barrier

    // Prime: sb = window(t_begin), G = window(t_begin+32)
    STAGE(G);
    GLOAD(G, t_begin + 32);

    float k1 = 0.f, k2 = 0.f, v = 0.f;

    // ---------------- warmup: 0 or 3 windows, z discarded ----------------
    for (int tb = t_begin; tb < t_out; tb += 32) {
        #pragma unroll
        for (int t2 = 0; t2 < 32; ++t2)
            step_one(sb[lbase + t2], k1, k2, v, s_tabS);
        ds_fence();                                // window reads retired
        STAGE(G);                                  // sb <- window(tb+32)
        GLOAD(G, tb + 64);                         // <= t_out+32 <= 1952 ok
    }

    // ---------------- output: 4 windows of 32 steps ----------------
    float zz[32];
    #pragma unroll
    for (int kw = 0; kw < 4; ++kw) {
        #pragma unroll
        for (int t2 = 0; t2 < 32; ++t2)
            zz[t2] = step_one(sb[lbase + t2], k1, k2, v, s_tabS);
        ds_fence();                                // window reads retired
        FLUSH(kw);                                 // cols [t_out+1+32kw, +32)
        if (kw == 3) break;
        STAGE(G);                                  // sb <- next window
        int tn = t_out + 32 * kw + 64;             // clamp: tail of c=15
        if (tn > Tlen - 32) tn = Tlen - 32;
        GLOAD(G, tn);
    }
}

// ------------------------------ launcher -----------------------------------
extern "C" void kernel_launch(void* const* d_in, const int* in_sizes, int n_in,
                              void* d_out, int out_size, void* d_ws, size_t ws_size,
                              hipStream_t stream) {
    const float* u = (const float*)d_in[0];
    float* out = (float*)d_out;
    float* ws  = (float*)d_ws;                     // needs ~9 KB
    setup_kernel<<<32, 256, 0, stream>>>(ws, out);
    sim_kernel<<<SIM_GRID, BLOCK, 0, stream>>>(u, ws, out);
}

// Round 12
// 144.243 us; speedup vs baseline: 1.3257x; 1.0042x over previous
//
#include <hip/hip_runtime.h>
#include <math.h>

// ---------------------------------------------------------------------------
// TwoDimEquivalent: B=8192 independent nonlinear scans of length T=2048.
// R17: ROW-STEP REDUCTION (the one untested lever).
//   Model after R15/R16: not byte-bound (R16: fewer bytes, MORE time), not
//   wave-issue-bound (R15: 2x wave-steps free), not TLP-bound. Binding
//   resource scales with ROW-STEPS (~1.7 us/M warm). Graded pinned at
//   145+-1.5 for 5 diverse kernels (warm 53-87) -> only gross work moved it.
//   Cut: CHUNKS 16->8 (CLEN=256) + WARM=96: 3968 -> 2720 steps/row (x0.69).
//  * TLP held at proven point (2048 waves, 2/SIMD): 32 rows/wave, lanes
//    l and l+32 DUPLICATE (R15-proven; distinct global addrs, LDS bcast).
//  * Chassis = R12 (best warm 55.9/graded 145.3): float2 pair-table gather
//    (1 ds_read_b64/step), READBACK u-window into regs (1 lgkm wait/32
//    steps), flush z through sb scratch when free, wave-autonomous, no
//    main-loop barriers, vmcnt never drained. R16's combo (no-READBACK +
//    scalar table + flush-32 on 64-row chassis) warm-regressed 55->86:
//    reverted wholesale.
//  * LDS: 16 KB pair tab + 4 x 4.2 KB staging = 33.3 KB. VGPR ~100.
//  * Per window (32 steps): READBACK -> [FLUSH prev zz] -> STAGE -> GLOAD
//    -> 32 reg-fed steps. FLUSH uses sb as transpose scratch post-READBACK.
// History: R5 151.9. R8 LLC null. R9 counted barriers (cold 147->58).
// R10 lockstep-TLP regress. R11/R12 nulls at 55. R13 poly VALU 64/175.
// R14 spill. R15 2x waves null -> row-step binder. R16 combo pathology
// (warm 86) but graded 144.8 best = plateau evidence.
// R17 predict: warm 38-45, graded 105-135 if work-coupled; if ~145 again
// -> environmental floor -> declare ROOFLINE next round.
// ---------------------------------------------------------------------------

#define Bsz   8192
#define Tlen  2048
#define TP1   2049
#define NQ    64
#define NG    2049                // scalar g samples, s = j/32 on [0,64]
#define NTAB2 2048                // float2 pair entries (16 KB)
#define INV_H 32.0f
#define CHUNKS 8
#define CLEN  256
#define WARM  96                  // 3 windows; passed at absmax 0.0098 (R16)
#define BLOCK 256
#define RPW   32                  // rows per wave (lanes l,l+32 duplicate)
#define SROW  33                  // staging row stride (floats)
#define SIM_GRID (64 * CHUNKS)    // 512: 64 row-blocks(128 rows) x 8 chunks

#define WS_TAB 128                // scalar g table offset (floats) in d_ws

// LDS-visibility barrier (after tab fill only); vmcnt NOT drained.
__device__ __forceinline__ void bar_nodrain() {
    asm volatile("s_waitcnt lgkmcnt(0)" ::: "memory");
    __builtin_amdgcn_s_barrier();
}
// Intra-wave DS fence: all my ds ops complete; compiler may not reorder.
__device__ __forceinline__ void ds_fence() {
    asm volatile("s_waitcnt lgkmcnt(0)" ::: "memory");
}

// --------------------------- setup: build LUT ------------------------------
__global__ __launch_bounds__(256) void setup_kernel(float* __restrict__ ws,
                                                    float* __restrict__ out) {
    __shared__ float  fx[NQ], fw[NQ];
    __shared__ double inv[NQ + 1];
    const int tid = threadIdx.x;
    if (tid <= NQ) inv[tid] = (tid == 0) ? 0.0 : 1.0 / (double)tid;
    __syncthreads();
    if (tid < NQ) {
        // Newton on P_64: guess err ~3e-4 -> 3 updates reach ~1e-15,
        // 4th pass evaluates pp at converged z (no update).
        double z = cos(3.14159265358979323846 * (tid + 0.75) / (NQ + 0.5));
        double p1 = 1.0, p2 = 0.0, pp = 1.0;
        for (int it = 0; it < 4; ++it) {
            p1 = 1.0; p2 = 0.0;
            for (int j = 1; j <= NQ; ++j) {
                double p3 = p2; p2 = p1;
                p1 = ((2.0 * j - 1.0) * z * p2 - (j - 1.0) * p3) * inv[j];
            }
            pp = NQ * (z * p1 - p2) / (z * z - 1.0);
            if (it < 3) z -= p1 / pp;
        }
        double w  = 2.0 / ((1.0 - z * z) * pp * pp);
        double xs = z * 5.0;                       // node scaled to [-5,5]
        fx[tid] = (float)xs;                       // f32 cast, like reference
        fw[tid] = (float)(w * 5.0 * exp(-0.5 * xs * xs) * 0.3989422804014327);
    }
    __syncthreads();
    const int j = blockIdx.x * 256 + tid;          // grid 32x256 = 8192
    if (j < NG) {                                  // g(s_j), s_j = j/32
        const float d = sqrtf((float)j * (1.0f / INV_H));
        float acc = 0.0f;
        #pragma unroll 8
        for (int q = 0; q < NQ; ++q) {
            float t = tanhf(d * fx[q]);
            acc = fmaf(fw[q], 1.0f - t * t, acc);
        }
        ws[WS_TAB + j] = acc;
    }
    out[(size_t)j * TP1] = 0.0f;                   // z_hist[:,0] = 0
}

// ------------------------------ main scan ----------------------------------
__device__ __forceinline__ float step_one(float uu, float& k1, float& k2,
                                          float& v, const float2* s_tab) {
    float s   = fmaf(k1, k1, fmaf(k2, k2, uu * uu));      // delta^2
    float idx = fminf(s * INV_H, 2046.999f);
    int   i0  = (int)idx;
    float f   = idx - (float)i0;
    float2 g2 = s_tab[i0];                                // one ds_read_b64
    float g   = fmaf(f, g2.y - g2.x, g2.x);               // gauss_int
    float gv  = g * v;
    float nk1 = fmaf(k1, fmaf(0.2f, g, 0.8f), 0.10f * gv);
    float nk2 = fmaf(k2, fmaf(0.1f, g, 0.8f), 0.38f * gv);
    v  = fmaf(0.2f, uu - v, v);
    k1 = nk1; k2 = nk2;
    return fmaf(2.8f, nk1, -2.2f * nk2);
}

// Load next window: 4 float4/lane; 64 lanes cover 32 rows x 128 B, each
// lane a DISTINCT 16 B (rows 8r+srow, srow=l>>3 in 0..7, scol=(l&7)*4).
#define GLOAD(G, t) { _Pragma("unroll")                                       \
    for (int r = 0; r < 4; ++r)                                               \
        G[r] = *(const float4*)(up + (size_t)r * 8 * Tlen + (t)); }

// Stage window into per-wave LDS buffer (16 ds_write_b32 per lane)
#define STAGE(G) { asm volatile("" ::: "memory");  _Pragma("unroll")          \
    for (int r = 0; r < 4; ++r) {                                             \
        int b8 = (8 * r + srow) * SROW + scol;                                \
        sb[b8] = G[r].x; sb[b8+1] = G[r].y; sb[b8+2] = G[r].z;                \
        sb[b8+3] = G[r].w; }                                                  \
    ds_fence(); }

// Batch the lane's 32-step u window into registers: ONE wait per window.
// Lanes l,l+32 read the same addresses (broadcast); 32 distinct rows hit
// banks (l+j)%32 -> conflict-free.
#define READBACK() { asm volatile("" ::: "memory"); _Pragma("unroll")         \
    for (int j = 0; j < 32; ++j) U[j] = sb[lbase + j];                        \
    ds_fence(); }

// Flush one 32-col window for the wave's 32 rows through sb scratch
// (sb must be free, i.e. after READBACK). Write: lanes<32, banks (l+j)%32.
// Read: rows 2kk,2kk+1 x 32 cols = 2 x 128 B contiguous per store.
#define FLUSH(kw) { const int cb = t_out + 1 + 32 * (kw);                     \
    asm volatile("" ::: "memory");                                            \
    if (l < 32) { _Pragma("unroll") for (int j = 0; j < 32; ++j)              \
        sb[lbase + j] = zz[j]; }                                              \
    ds_fence();                                                               \
    _Pragma("unroll") for (int kk = 0; kk < 16; ++kk) {                       \
        int row = 2 * kk + (l >> 5);                                          \
        out[(size_t)(rowb + row) * TP1 + cb + (l & 31)] =                     \
            sb[row * SROW + (l & 31)];                                        \
    }                                                                         \
    ds_fence(); }

__global__ __launch_bounds__(BLOCK, 2) void sim_kernel(const float* __restrict__ u,
                                                       const float* __restrict__ ws,
                                                       float* __restrict__ out) {
    __shared__ float2 s_tab[NTAB2];                // 16 KB pair table
    __shared__ float  s_st[4][RPW * SROW];         // 4 x 4.2 KB per-wave bufs
    const int tid = threadIdx.x;
    const int w   = tid >> 6;                      // wave id (4)
    const int l   = tid & 63;                      // lane
    float* sb = s_st[w];

    const int c    = blockIdx.x >> 6;              // chunk id (8)
    const int rb   = blockIdx.x & 63;              // row-block id (64)
    const int rowb = rb * 128 + w * RPW;           // wave's first row
    const int t_out   = c * CLEN;                  // first owned step
    const int t_begin = (t_out >= WARM) ? (t_out - WARM) : 0;   // c=0 -> 0

    // staging lane map: lane l covers row (8r + srow), 16 B at offset scol
    const int srow = l >> 3;                       // 0..7
    const int scol = (l & 7) * 4;                  // 0,4,...,28
    const float* __restrict__ up = u + (size_t)(rowb + srow) * Tlen + scol;
    const int lbase = (l & 31) * SROW;             // my row's staging base

    // Issue the first window FIRST so cold misses start immediately.
    float4 G[4];
    GLOAD(G, t_begin);

    {   // pair-table fill from scalar g[] in ws (coalesced float4 + 1 scalar)
        const float* g = ws + WS_TAB;
        #pragma unroll
        for (int i = 0; i < NTAB2 / (BLOCK * 4); ++i) {   // 2 iters
            int k = (i * BLOCK + tid) * 4;
            float4 a = *(const float4*)(g + k);
            float  b = g[k + 4];
            s_tab[k + 0] = make_float2(a.x, a.y);
            s_tab[k + 1] = make_float2(a.y, a.z);
            s_tab[k + 2] = make_float2(a.z, a.w);
            s_tab[k + 3] = make_float2(a.w, b);
        }
    }
    bar_nodrain();                                 // the ONLY block barrier

    // Prime: sb = window(t_begin), G = window(t_begin+32)
    STAGE(G);
    GLOAD(G, t_begin + 32);

    float k1 = 0.f, k2 = 0.f, v = 0.f;
    float U[32];                                   // register u window

    // ---------------- warmup: 0 or 3 windows, z discarded ----------------
    for (int tb = t_begin; tb < t_out; tb += 32) {
        READBACK();                                // U <- window(tb)
        STAGE(G);                                  // sb <- window(tb+32)
        GLOAD(G, tb + 64);                         // <= t_out+32 <= 1824, ok
        #pragma unroll
        for (int t2 = 0; t2 < 32; ++t2)
            step_one(U[t2], k1, k2, v, s_tab);
    }

    // ---------------- output: 8 windows of 32 steps ----------------
    float zz[32];
    #pragma unroll
    for (int kw = 0; kw < 8; ++kw) {
        const int tb = t_out + 32 * kw;
        READBACK();                                // U <- window(tb); sb free
        if (kw > 0) FLUSH(kw - 1);                 // flush previous window's z
        STAGE(G);                                  // sb <- window(tb+32)
        int tn = tb + 64;                          // clamp: tail of c=7
        if (tn > Tlen - 32) tn = Tlen - 32;
        GLOAD(G, tn);
        #pragma unroll
        for (int t2 = 0; t2 < 32; ++t2)
            zz[t2] = step_one(U[t2], k1, k2, v, s_tab);
    }
    FLUSH(7);                                      // last window's z
}

// ------------------------------ launcher -----------------------------------
extern "C" void kernel_launch(void* const* d_in, const int* in_sizes, int n_in,
                              void* d_out, int out_size, void* d_ws, size_t ws_size,
                              hipStream_t stream) {
    const float* u = (const float*)d_in[0];
    float* out = (float*)d_out;
    float* ws  = (float*)d_ws;                     // needs ~9 KB
    setup_kernel<<<32, 256, 0, stream>>>(ws, out);
    sim_kernel<<<SIM_GRID, BLOCK, 0, stream>>>(u, ws, out);
}